// Round 13
// baseline (502.081 us; speedup 1.0000x reference)
//
#include <hip/hip_runtime.h>
#include <cstddef>
#include <cstdint>

// STGCN v5: v4 + latency-hiding in the MFMA kernels (v4 PMC: conv MfmaUtil 35%,
// VALU 19%, HBM 10% -> dependency-latency-bound):
//   - T14 async-stage split: next half/phase global loads issued into regs
//     BEFORE current compute; LDS write after the post-compute barrier.
//   - 2-deep B prefetch queue, two named slots (A=even step, B=odd step) so
//     all register indexing is compile-time (rule #20).
// Tiles stay 64 nodes x 128 outs (grid 782). agg/clf/CSR unchanged from v4.

#define N_NODES 50000
#define FDIM    128
#define OUTC    64
#define NLAYER  3
#define KW      9
#define PADW    4
#define NEDGE   600000
#define BN_EPS  1e-5f

typedef short bf16x8 __attribute__((ext_vector_type(8)));
typedef float f32x4  __attribute__((ext_vector_type(4)));

__device__ __forceinline__ float relu_(float v){ return v > 0.f ? v : 0.f; }

__device__ __forceinline__ unsigned short bf_rne(float x){
  unsigned u = __float_as_uint(x);
  unsigned r = u + 0x7fff + ((u >> 16) & 1);
  return (unsigned short)(r >> 16);
}
__device__ __forceinline__ unsigned short bf_hi(float x, float& rem){
  unsigned short h = bf_rne(x);
  rem = x - __uint_as_float(((unsigned)h) << 16);
  return h;
}
__device__ __forceinline__ float bf2f(unsigned short u){
  return __uint_as_float(((unsigned)u) << 16);
}
__device__ __forceinline__ void cvt8(const float4& f0, const float4& f1, int4& hv, int4& lv){
  float f[8] = {f0.x,f0.y,f0.z,f0.w,f1.x,f1.y,f1.z,f1.w};
  unsigned short h[8], l[8];
  #pragma unroll
  for (int i=0;i<8;i++){ float r; h[i] = bf_hi(f[i], r); l[i] = bf_rne(r); }
  hv.x = (int)((unsigned)h[0] | ((unsigned)h[1]<<16));
  hv.y = (int)((unsigned)h[2] | ((unsigned)h[3]<<16));
  hv.z = (int)((unsigned)h[4] | ((unsigned)h[5]<<16));
  hv.w = (int)((unsigned)h[6] | ((unsigned)h[7]<<16));
  lv.x = (int)((unsigned)l[0] | ((unsigned)l[1]<<16));
  lv.y = (int)((unsigned)l[2] | ((unsigned)l[3]<<16));
  lv.z = (int)((unsigned)l[4] | ((unsigned)l[5]<<16));
  lv.w = (int)((unsigned)l[6] | ((unsigned)l[7]<<16));
}

// ---------------- edge dtype detect + CSR build ----------------

__global__ void k_detect(const int* __restrict__ ei, int* __restrict__ flag){
  int t = threadIdx.x;
  unsigned long long b = __ballot(ei[2*t+1] == 0);
  if (t == 0) flag[0] = (b == ~0ull) ? 1 : 0;
}

__global__ void k_zero(int* __restrict__ p, int n){
  int i = blockIdx.x*256 + threadIdx.x;
  if (i < n) p[i] = 0;
}

__global__ void k_deg(const int* __restrict__ ei, const int* __restrict__ flag, int* __restrict__ deg){
  int e = blockIdx.x*256 + threadIdx.x;
  if (e >= NEDGE) return;
  int d = flag[0] ? ei[2*(NEDGE+e)] : ei[NEDGE+e];
  atomicAdd(&deg[d], 1);
}

__global__ void k_scan1(const int* __restrict__ deg, int* __restrict__ rp, int* __restrict__ bsums){
  __shared__ int sd[256];
  int t = threadIdx.x, base = blockIdx.x*1024 + t*4;
  int v0=0,v1=0,v2=0,v3=0;
  if (base+3 < N_NODES){ int4 q = *(const int4*)(deg+base); v0=q.x; v1=q.y; v2=q.z; v3=q.w; }
  else {
    if (base   < N_NODES) v0 = deg[base];
    if (base+1 < N_NODES) v1 = deg[base+1];
    if (base+2 < N_NODES) v2 = deg[base+2];
    if (base+3 < N_NODES) v3 = deg[base+3];
  }
  int s = v0+v1+v2+v3;
  sd[t] = s; __syncthreads();
  #pragma unroll
  for (int o=1;o<256;o<<=1){
    int x = (t>=o) ? sd[t-o] : 0;
    __syncthreads();
    sd[t] += x;
    __syncthreads();
  }
  int excl = sd[t]-s;
  if (base   < N_NODES) rp[base  ] = excl;
  if (base+1 < N_NODES) rp[base+1] = excl+v0;
  if (base+2 < N_NODES) rp[base+2] = excl+v0+v1;
  if (base+3 < N_NODES) rp[base+3] = excl+v0+v1+v2;
  if (t==255) bsums[blockIdx.x] = sd[255];
}

__global__ void k_scan2(int* __restrict__ bsums, int nb){
  if (threadIdx.x==0 && blockIdx.x==0){
    int run = 0;
    for (int i=0;i<nb;i++){ int x = bsums[i]; bsums[i] = run; run += x; }
  }
}

__global__ void k_scan3(int* __restrict__ rp, int* __restrict__ cur, float* __restrict__ idg,
                        const int* __restrict__ deg, const int* __restrict__ bsums){
  int i = blockIdx.x*256 + threadIdx.x;
  if (i < N_NODES){
    int r = rp[i] + bsums[i>>10];
    rp[i] = r; cur[i] = r;
    int d = deg[i];
    idg[i] = (d>0) ? 1.0f/(float)d : 0.0f;
  } else if (i == N_NODES){
    rp[N_NODES] = NEDGE;
  }
}

__global__ void k_fill(const int* __restrict__ ei, const int* __restrict__ flag,
                       int* __restrict__ cur, int* __restrict__ col){
  int e = blockIdx.x*256 + threadIdx.x;
  if (e >= NEDGE) return;
  int s,d;
  if (flag[0]){ s = ei[2*e]; d = ei[2*(NEDGE+e)]; }
  else        { s = ei[e];   d = ei[NEDGE+e];   }
  int pos = atomicAdd(&cur[d], 1);
  col[pos] = s;
}

// ---------------- weight prepack into MFMA fragment chunks ----------------

__global__ void k_pack(const float* __restrict__ tw, const float* __restrict__ wl,
                       const float* __restrict__ wr, const float* __restrict__ cw,
                       unsigned short* __restrict__ wp, unsigned short* __restrict__ wg,
                       float* __restrict__ cwt){
  int i = blockIdx.x*256 + threadIdx.x;
  const int T1v = 442368, T2v = 98304, T3v = 8192;
  if (i < T1v){
    int e = i & 7, lane = (i>>3)&63, ob = (i>>9)&7, cb = (i>>12)&3, kl = i>>14;
    int k = kl % KW, l = kl / KW;
    int o = ob*16 + (lane&15), c = cb*32 + (lane>>4)*8 + e;
    float v = tw[(((l*128+o)*128+c)*KW) + k];
    float rem; unsigned short hi = bf_hi(v, rem); unsigned short lo = bf_rne(rem);
    int chunk = (((l*KW+k)*4+cb)*8+ob)*2;
    wp[(size_t)chunk*512 + lane*8 + e]     = hi;
    wp[(size_t)(chunk+1)*512 + lane*8 + e] = lo;
  } else if (i < T1v+T2v){
    int i2 = i - T1v;
    int e = i2 & 7, lane = (i2>>3)&63, ob = (i2>>9)&7, ks = (i2>>12)&7, l = i2>>15;
    int o = ob*16 + (lane&15), j = ks*32 + (lane>>4)*8 + e;
    float v = (j < 128) ? wl[(l*128+o)*128 + j] : wr[(l*128+o)*128 + (j-128)];
    float rem; unsigned short hi = bf_hi(v, rem); unsigned short lo = bf_rne(rem);
    int chunk = ((l*8+ks)*8+ob)*2;
    wg[(size_t)chunk*512 + lane*8 + e]     = hi;
    wg[(size_t)(chunk+1)*512 + lane*8 + e] = lo;
  } else if (i < T1v+T2v+T3v){
    int j3 = i - (T1v+T2v);
    int o = j3 & 63, c = j3 >> 6;
    cwt[j3] = cw[o*128 + c];
  }
}

// ---------------- conv via MFMA: 64-node tile, async-stage + 2-deep B queue ----

#define CROWS 72

__global__ __launch_bounds__(256, 4) void k_convm(const float* __restrict__ xf,
                                                  const unsigned short* __restrict__ xhi,
                                                  const unsigned short* __restrict__ xlo,
                                                  const int use_planes,
                                                  const unsigned short* __restrict__ wpl,
                                                  const float* __restrict__ tb,
                                                  unsigned short* __restrict__ hhi,
                                                  unsigned short* __restrict__ hlo){
  __shared__ unsigned short sh[2*CROWS*64];     // 18432 B
  const int t = threadIdx.x;
  const int n0 = blockIdx.x*64;
  const int l = t & 63, w = t >> 6;
  const int l15 = l & 15, kg = l >> 4;
  const bf16x8* Bp = (const bf16x8*)wpl;

  f32x4 acc[4][2];
  #pragma unroll
  for (int rf=0;rf<4;rf++){ acc[rf][0] = (f32x4)0.f; acc[rf][1] = (f32x4)0.f; }

  // staging slots: 3 per thread (576 row-chunks / 256 threads)
  int4 sA[3], sB[3];
  auto stage_load = [&](int half){
    #pragma unroll
    for (int i=0;i<3;i++){
      int u = t + i*256;
      sA[i] = make_int4(0,0,0,0); sB[i] = make_int4(0,0,0,0);
      if (u < CROWS*8){
        int row = u>>3, c8 = u&7;
        int gn = n0 - PADW + row;
        if (gn >= 0 && gn < N_NODES){
          if (use_planes){
            size_t o = (size_t)gn*FDIM + half*64 + c8*8;
            sA[i] = *(const int4*)(xhi + o);
            sB[i] = *(const int4*)(xlo + o);
          } else {
            const float* src = xf + (size_t)gn*FDIM + half*64 + c8*8;
            sA[i] = *(const int4*)src;
            sB[i] = *(const int4*)(src+4);
          }
        }
      }
    }
  };
  auto stage_write = [&](){
    #pragma unroll
    for (int i=0;i<3;i++){
      int u = t + i*256;
      if (u < CROWS*8){
        int row = u>>3, c8 = u&7;
        int idx = row*64 + ((c8 ^ (row&7)) << 3);
        int4 hv, lv;
        if (use_planes){ hv = sA[i]; lv = sB[i]; }
        else {
          float4 f0 = *(float4*)&sA[i], f1 = *(float4*)&sB[i];
          cvt8(f0, f1, hv, lv);
        }
        *(int4*)&sh[idx] = hv;
        *(int4*)&sh[CROWS*64 + idx] = lv;
      }
    }
  };

  // B chunk address for step it (0..35): halfn=it/18, kkn=it%18
  auto chbase = [&](int it)->int{
    int halfn = it/18, kkn = it%18;
    int kn = kkn>>1, cb2n = kkn&1, cbgn = halfn*2 + cb2n;
    return ((kn*4+cbgn)*8 + 2*w)*2;
  };

  // 2-deep B queue: slot A = even it, slot B = odd it
  bf16x8 BA0,BA1,BA2,BA3, BB0,BB1,BB2,BB3;
  { int ch = chbase(0);
    BA0 = Bp[ch*64+l]; BA1 = Bp[(ch+1)*64+l]; BA2 = Bp[(ch+2)*64+l]; BA3 = Bp[(ch+3)*64+l]; }
  { int ch = chbase(1);
    BB0 = Bp[ch*64+l]; BB1 = Bp[(ch+1)*64+l]; BB2 = Bp[(ch+2)*64+l]; BB3 = Bp[(ch+3)*64+l]; }

  stage_load(0);
  stage_write();
  __syncthreads();

  for (int half = 0; half < 2; ++half){
    if (half == 0) stage_load(1);          // issue next half's loads early (T14)
    for (int kk2 = 0; kk2 < 18; kk2 += 2){
      int k = kk2 >> 1;
      int rowk = l15 + k;
      // ---- step A: it = half*18+kk2, cb2=0 ----
      {
        bf16x8 Bc0=BA0, Bc1=BA1, Bc2=BA2, Bc3=BA3;
        int itn = half*18 + kk2 + 2; if (itn > 35) itn = 35;
        int ch = chbase(itn);
        BA0 = Bp[ch*64+l]; BA1 = Bp[(ch+1)*64+l]; BA2 = Bp[(ch+2)*64+l]; BA3 = Bp[(ch+3)*64+l];
        int base = rowk*64 + ((kg ^ (rowk&7)) << 3);
        #pragma unroll
        for (int rf = 0; rf < 4; ++rf){
          int idx = base + rf*16*64;
          bf16x8 Ah = *(const bf16x8*)&sh[idx];
          bf16x8 Al = *(const bf16x8*)&sh[CROWS*64 + idx];
          acc[rf][0] = __builtin_amdgcn_mfma_f32_16x16x32_bf16(Ah, Bc0, acc[rf][0], 0,0,0);
          acc[rf][0] = __builtin_amdgcn_mfma_f32_16x16x32_bf16(Ah, Bc1, acc[rf][0], 0,0,0);
          acc[rf][0] = __builtin_amdgcn_mfma_f32_16x16x32_bf16(Al, Bc0, acc[rf][0], 0,0,0);
          acc[rf][1] = __builtin_amdgcn_mfma_f32_16x16x32_bf16(Ah, Bc2, acc[rf][1], 0,0,0);
          acc[rf][1] = __builtin_amdgcn_mfma_f32_16x16x32_bf16(Ah, Bc3, acc[rf][1], 0,0,0);
          acc[rf][1] = __builtin_amdgcn_mfma_f32_16x16x32_bf16(Al, Bc2, acc[rf][1], 0,0,0);
        }
      }
      // ---- step B: it = half*18+kk2+1, cb2=1 ----
      {
        bf16x8 Bc0=BB0, Bc1=BB1, Bc2=BB2, Bc3=BB3;
        int itn = half*18 + kk2 + 3; if (itn > 35) itn = 35;
        int ch = chbase(itn);
        BB0 = Bp[ch*64+l]; BB1 = Bp[(ch+1)*64+l]; BB2 = Bp[(ch+2)*64+l]; BB3 = Bp[(ch+3)*64+l];
        int cc3 = 4 + kg;
        int base = rowk*64 + ((cc3 ^ (rowk&7)) << 3);
        #pragma unroll
        for (int rf = 0; rf < 4; ++rf){
          int idx = base + rf*16*64;
          bf16x8 Ah = *(const bf16x8*)&sh[idx];
          bf16x8 Al = *(const bf16x8*)&sh[CROWS*64 + idx];
          acc[rf][0] = __builtin_amdgcn_mfma_f32_16x16x32_bf16(Ah, Bc0, acc[rf][0], 0,0,0);
          acc[rf][0] = __builtin_amdgcn_mfma_f32_16x16x32_bf16(Ah, Bc1, acc[rf][0], 0,0,0);
          acc[rf][0] = __builtin_amdgcn_mfma_f32_16x16x32_bf16(Al, Bc0, acc[rf][0], 0,0,0);
          acc[rf][1] = __builtin_amdgcn_mfma_f32_16x16x32_bf16(Ah, Bc2, acc[rf][1], 0,0,0);
          acc[rf][1] = __builtin_amdgcn_mfma_f32_16x16x32_bf16(Ah, Bc3, acc[rf][1], 0,0,0);
          acc[rf][1] = __builtin_amdgcn_mfma_f32_16x16x32_bf16(Al, Bc2, acc[rf][1], 0,0,0);
        }
      }
    }
    if (half == 0){
      __syncthreads();      // all reads of half-0 LDS done
      stage_write();        // loads had the whole half-0 compute to land
      __syncthreads();
    }
  }

  int o0 = w*32 + l15, o1 = o0 + 16;
  float tb0 = tb[o0], tb1 = tb[o1];
  #pragma unroll
  for (int rf = 0; rf < 4; ++rf){
    #pragma unroll
    for (int j = 0; j < 4; ++j){
      int n = n0 + rf*16 + kg*4 + j;
      if (n < N_NODES){
        float v0 = relu_(acc[rf][0][j] + tb0);
        float v1 = relu_(acc[rf][1][j] + tb1);
        float r0, r1;
        unsigned short h0 = bf_hi(v0, r0), h1 = bf_hi(v1, r1);
        size_t b = (size_t)n*FDIM;
        hhi[b+o0] = h0; hlo[b+o0] = bf_rne(r0);
        hhi[b+o1] = h1; hlo[b+o1] = bf_rne(r1);
      }
    }
  }
}

// ---------------- SAGE mean aggregation: bf16-hi gather (as v4) ----------------

__global__ __launch_bounds__(256) void k_agg(const unsigned short* __restrict__ hhi,
                                             const int* __restrict__ rp,
                                             const int* __restrict__ col,
                                             const float* __restrict__ idg,
                                             unsigned short* __restrict__ ahi,
                                             unsigned short* __restrict__ alo){
  int n = blockIdx.x*4 + (threadIdx.x>>6);
  int lane = threadIdx.x & 63;
  int half = lane >> 5, li = lane & 31;
  if (n >= N_NODES) return;
  int s0 = rp[n], s1 = rp[n+1];
  float a0=0.f, a1=0.f, a2=0.f, a3=0.f;
  int e = s0 + half;
  for (; e + 2 < s1; e += 4){
    int sA = col[e], sB = col[e+2];
    ushort4 vA = *(const ushort4*)(hhi + (size_t)sA*FDIM + li*4);
    ushort4 vB = *(const ushort4*)(hhi + (size_t)sB*FDIM + li*4);
    a0 += bf2f(vA.x) + bf2f(vB.x);
    a1 += bf2f(vA.y) + bf2f(vB.y);
    a2 += bf2f(vA.z) + bf2f(vB.z);
    a3 += bf2f(vA.w) + bf2f(vB.w);
  }
  for (; e < s1; e += 2){
    int s = col[e];
    ushort4 v = *(const ushort4*)(hhi + (size_t)s*FDIM + li*4);
    a0 += bf2f(v.x); a1 += bf2f(v.y); a2 += bf2f(v.z); a3 += bf2f(v.w);
  }
  a0 += __shfl_xor(a0, 32);
  a1 += __shfl_xor(a1, 32);
  a2 += __shfl_xor(a2, 32);
  a3 += __shfl_xor(a3, 32);
  float wv = idg[n];
  a0 *= wv; a1 *= wv; a2 *= wv; a3 *= wv;
  float r0,r1,r2,r3;
  unsigned short h0 = bf_hi(a0,r0), h1 = bf_hi(a1,r1), h2 = bf_hi(a2,r2), h3 = bf_hi(a3,r3);
  size_t b = (size_t)n*FDIM + li*4;
  if (half == 0){
    ushort4 o; o.x=h0; o.y=h1; o.z=h2; o.w=h3;
    *(ushort4*)(ahi + b) = o;
  } else {
    ushort4 o; o.x=bf_rne(r0); o.y=bf_rne(r1); o.z=bf_rne(r2); o.w=bf_rne(r3);
    *(ushort4*)(alo + b) = o;
  }
}

// ---------------- SAGE linear + BN + ReLU: async-stage + 2-deep B queue -------

__global__ __launch_bounds__(256, 4) void k_gemmm(const unsigned short* __restrict__ ahi,
                                                  const unsigned short* __restrict__ alo,
                                                  const unsigned short* __restrict__ hhi,
                                                  const unsigned short* __restrict__ hlo,
                                                  const unsigned short* __restrict__ wgl,
                                                  const float* __restrict__ bl,
                                                  const float* __restrict__ bng, const float* __restrict__ bnb,
                                                  const float* __restrict__ bnm, const float* __restrict__ bnv,
                                                  unsigned short* __restrict__ xhi,
                                                  unsigned short* __restrict__ xlo){
  __shared__ unsigned short sh[2*64*64];        // 16384 B
  const int t = threadIdx.x;
  const int n0 = blockIdx.x*64;
  const int l = t & 63, w = t >> 6;
  const int l15 = l & 15, kg = l >> 4;
  const bf16x8* Bp = (const bf16x8*)wgl;

  f32x4 acc[4][2];
  #pragma unroll
  for (int rf=0;rf<4;rf++){ acc[rf][0] = (f32x4)0.f; acc[rf][1] = (f32x4)0.f; }

  // staging slots: exactly 2 per thread (512 row-chunks / 256 threads)
  int4 sA2[2], sB2[2];
  auto stage_load = [&](int p){
    const unsigned short* shi = (p >= 2) ? hhi : ahi;
    const unsigned short* slo = (p >= 2) ? hlo : alo;
    int ch0 = (p & 1)*64;
    #pragma unroll
    for (int i=0;i<2;i++){
      int u = t + i*256;
      int row = u>>3, c8 = u&7;
      int gn = n0 + row;
      sA2[i] = make_int4(0,0,0,0); sB2[i] = make_int4(0,0,0,0);
      if (gn < N_NODES){
        size_t o = (size_t)gn*FDIM + ch0 + c8*8;
        sA2[i] = *(const int4*)(shi + o);
        sB2[i] = *(const int4*)(slo + o);
      }
    }
  };
  auto stage_write = [&](){
    #pragma unroll
    for (int i=0;i<2;i++){
      int u = t + i*256;
      int row = u>>3, c8 = u&7;
      int idx = row*64 + ((c8 ^ (row&7)) << 3);
      *(int4*)&sh[idx] = sA2[i];
      *(int4*)&sh[64*64 + idx] = sB2[i];
    }
  };
  auto chbase = [&](int ks)->int{ return (ks*8 + 2*w)*2; };

  bf16x8 BA0,BA1,BA2,BA3, BB0,BB1,BB2,BB3;
  { int ch = chbase(0);
    BA0 = Bp[ch*64+l]; BA1 = Bp[(ch+1)*64+l]; BA2 = Bp[(ch+2)*64+l]; BA3 = Bp[(ch+3)*64+l]; }
  { int ch = chbase(1);
    BB0 = Bp[ch*64+l]; BB1 = Bp[(ch+1)*64+l]; BB2 = Bp[(ch+2)*64+l]; BB3 = Bp[(ch+3)*64+l]; }

  stage_load(0);
  stage_write();
  __syncthreads();

  for (int p = 0; p < 4; ++p){
    if (p < 3) stage_load(p+1);            // issue next phase's loads early (T14)
    // ---- step A: ks = 2p, cb2=0 ----
    {
      bf16x8 Bc0=BA0, Bc1=BA1, Bc2=BA2, Bc3=BA3;
      int ksn = 2*p + 2; if (ksn > 7) ksn = 7;
      int ch = chbase(ksn);
      BA0 = Bp[ch*64+l]; BA1 = Bp[(ch+1)*64+l]; BA2 = Bp[(ch+2)*64+l]; BA3 = Bp[(ch+3)*64+l];
      int base = l15*64 + ((kg ^ (l15&7)) << 3);
      #pragma unroll
      for (int rf = 0; rf < 4; ++rf){
        int idx = base + rf*16*64;
        bf16x8 Ah = *(const bf16x8*)&sh[idx];
        bf16x8 Al = *(const bf16x8*)&sh[64*64 + idx];
        acc[rf][0] = __builtin_amdgcn_mfma_f32_16x16x32_bf16(Ah, Bc0, acc[rf][0], 0,0,0);
        acc[rf][0] = __builtin_amdgcn_mfma_f32_16x16x32_bf16(Ah, Bc1, acc[rf][0], 0,0,0);
        acc[rf][0] = __builtin_amdgcn_mfma_f32_16x16x32_bf16(Al, Bc0, acc[rf][0], 0,0,0);
        acc[rf][1] = __builtin_amdgcn_mfma_f32_16x16x32_bf16(Ah, Bc2, acc[rf][1], 0,0,0);
        acc[rf][1] = __builtin_amdgcn_mfma_f32_16x16x32_bf16(Ah, Bc3, acc[rf][1], 0,0,0);
        acc[rf][1] = __builtin_amdgcn_mfma_f32_16x16x32_bf16(Al, Bc2, acc[rf][1], 0,0,0);
      }
    }
    // ---- step B: ks = 2p+1, cb2=1 ----
    {
      bf16x8 Bc0=BB0, Bc1=BB1, Bc2=BB2, Bc3=BB3;
      int ksn = 2*p + 3; if (ksn > 7) ksn = 7;
      int ch = chbase(ksn);
      BB0 = Bp[ch*64+l]; BB1 = Bp[(ch+1)*64+l]; BB2 = Bp[(ch+2)*64+l]; BB3 = Bp[(ch+3)*64+l];
      int cc3 = 4 + kg;
      int base = l15*64 + ((cc3 ^ (l15&7)) << 3);
      #pragma unroll
      for (int rf = 0; rf < 4; ++rf){
        int idx = base + rf*16*64;
        bf16x8 Ah = *(const bf16x8*)&sh[idx];
        bf16x8 Al = *(const bf16x8*)&sh[64*64 + idx];
        acc[rf][0] = __builtin_amdgcn_mfma_f32_16x16x32_bf16(Ah, Bc0, acc[rf][0], 0,0,0);
        acc[rf][0] = __builtin_amdgcn_mfma_f32_16x16x32_bf16(Ah, Bc1, acc[rf][0], 0,0,0);
        acc[rf][0] = __builtin_amdgcn_mfma_f32_16x16x32_bf16(Al, Bc0, acc[rf][0], 0,0,0);
        acc[rf][1] = __builtin_amdgcn_mfma_f32_16x16x32_bf16(Ah, Bc2, acc[rf][1], 0,0,0);
        acc[rf][1] = __builtin_amdgcn_mfma_f32_16x16x32_bf16(Ah, Bc3, acc[rf][1], 0,0,0);
        acc[rf][1] = __builtin_amdgcn_mfma_f32_16x16x32_bf16(Al, Bc2, acc[rf][1], 0,0,0);
      }
    }
    if (p < 3){
      __syncthreads();
      stage_write();
      __syncthreads();
    }
  }

  int o0 = w*32 + l15, o1 = o0 + 16;
  float s0 = bng[o0]*rsqrtf(bnv[o0]+BN_EPS);
  float c0 = bnb[o0] + s0*(bl[o0]-bnm[o0]);
  float s1 = bng[o1]*rsqrtf(bnv[o1]+BN_EPS);
  float c1 = bnb[o1] + s1*(bl[o1]-bnm[o1]);
  #pragma unroll
  for (int rf = 0; rf < 4; ++rf){
    #pragma unroll
    for (int j = 0; j < 4; ++j){
      int n = n0 + rf*16 + kg*4 + j;
      if (n < N_NODES){
        float v0 = relu_(s0*acc[rf][0][j] + c0);
        float v1 = relu_(s1*acc[rf][1][j] + c1);
        float r0, r1;
        unsigned short h0 = bf_hi(v0, r0), h1 = bf_hi(v1, r1);
        size_t b = (size_t)n*FDIM;
        xhi[b+o0] = h0; xlo[b+o0] = bf_rne(r0);
        xhi[b+o1] = h1; xlo[b+o1] = bf_rne(r1);
      }
    }
  }
}

// ---------------- classifier + log_softmax (as v4) ----------------

__global__ __launch_bounds__(256) void k_clf(const unsigned short* __restrict__ xhi,
                                             const unsigned short* __restrict__ xlo,
                                             const float* __restrict__ cwt,
                                             const float* __restrict__ cb, float* __restrict__ out){
  __shared__ float As[128][68];
  __shared__ float mxl[64];
  const int t = threadIdx.x, n0 = blockIdx.x*64;
  const int ng = t & 15, og = t>>4;
  float acc[4][4];
  #pragma unroll
  for (int i=0;i<4;i++)
    #pragma unroll
    for (int j=0;j<4;j++) acc[i][j] = 0.f;

  for (int u=t; u<64*16; u+=256){
    int row = u>>4, c16 = u&15;
    int gn = n0 + row;
    int4 hv = make_int4(0,0,0,0), lv = make_int4(0,0,0,0);
    if (gn < N_NODES){
      size_t o = (size_t)gn*FDIM + c16*8;
      hv = *(const int4*)(xhi + o);
      lv = *(const int4*)(xlo + o);
    }
    const unsigned short* hs = (const unsigned short*)&hv;
    const unsigned short* ls = (const unsigned short*)&lv;
    #pragma unroll
    for (int j=0;j<8;j++) As[c16*8+j][row] = bf2f(hs[j]) + bf2f(ls[j]);
  }
  __syncthreads();
  #pragma unroll 2
  for (int c=0;c<128;c++){
    float aa[4] = {As[c][ng], As[c][ng+16], As[c][ng+32], As[c][ng+48]};
    float4 b = *(const float4*)(cwt + c*64 + og*4);
    float bb[4] = {b.x,b.y,b.z,b.w};
    #pragma unroll
    for (int i=0;i<4;i++)
      #pragma unroll
      for (int j=0;j<4;j++) acc[i][j] = fmaf(aa[i], bb[j], acc[i][j]);
  }
  __syncthreads();
  float4 cb4 = *(const float4*)(cb + og*4);
  float cbv[4] = {cb4.x,cb4.y,cb4.z,cb4.w};
  #pragma unroll
  for (int i=0;i<4;i++)
    #pragma unroll
    for (int j=0;j<4;j++) As[ng+16*i][og*4+j] = acc[i][j] + cbv[j];
  __syncthreads();
  if (t < 64){
    float mx = -1e30f;
    #pragma unroll 8
    for (int o=0;o<64;o++) mx = fmaxf(mx, As[t][o]);
    float se = 0.f;
    #pragma unroll 8
    for (int o=0;o<64;o++) se += expf(As[t][o]-mx);
    mxl[t] = mx + logf(se);
  }
  __syncthreads();
  #pragma unroll
  for (int v=0;v<4;v++){
    int q = t + v*256;
    int r = q>>4, o4 = (q&15)*4;
    int n = n0 + r;
    if (n < N_NODES){
      float4 L = *(const float4*)&As[r][o4];
      float m = mxl[r];
      float4 wv; wv.x = L.x-m; wv.y = L.y-m; wv.z = L.z-m; wv.w = L.w-m;
      *(float4*)(out + (size_t)n*OUTC + o4) = wv;
    }
  }
}

// ---------------- launch ----------------

extern "C" void kernel_launch(void* const* d_in, const int* in_sizes, int n_in,
                              void* d_out, int out_size, void* d_ws, size_t ws_size,
                              hipStream_t stream) {
  const float* x   = (const float*)d_in[0];
  const int*   ei  = (const int*)  d_in[1];
  const float* tw  = (const float*)d_in[2];
  const float* tb  = (const float*)d_in[3];
  const float* wl  = (const float*)d_in[4];
  const float* bl  = (const float*)d_in[5];
  const float* wr  = (const float*)d_in[6];
  const float* bng = (const float*)d_in[7];
  const float* bnb = (const float*)d_in[8];
  const float* bnm = (const float*)d_in[9];
  const float* bnv = (const float*)d_in[10];
  const float* cw  = (const float*)d_in[11];
  const float* cb  = (const float*)d_in[12];
  float* out = (float*)d_out;
  char* ws = (char*)d_ws;

  auto align256 = [](size_t v){ return (v + 255) & ~(size_t)255; };
  size_t off = 0;
  auto take = [&](size_t bytes){ size_t o = off; off += align256(bytes); return o; };
  const size_t PLANE = (size_t)N_NODES*FDIM*2;              // 12.8 MB
  unsigned short* xhi = (unsigned short*)(ws + take(PLANE));
  unsigned short* xlo = (unsigned short*)(ws + take(PLANE));
  unsigned short* hhi = (unsigned short*)(ws + take(PLANE));
  unsigned short* hlo = (unsigned short*)(ws + take(PLANE));
  unsigned short* ahi = (unsigned short*)(ws + take(PLANE));
  unsigned short* alo = (unsigned short*)(ws + take(PLANE));
  unsigned short* wp  = (unsigned short*)(ws + take((size_t)884736*2));
  unsigned short* wg  = (unsigned short*)(ws + take((size_t)196608*2));
  float* cwt   = (float*)(ws + take((size_t)128*64*4));
  int*   deg   = (int*)  (ws + take((size_t)N_NODES*4));
  int*   rp    = (int*)  (ws + take((size_t)(N_NODES+1)*4));
  int*   cur   = (int*)  (ws + take((size_t)N_NODES*4));
  int*   col   = (int*)  (ws + take((size_t)NEDGE*4));
  float* idg   = (float*)(ws + take((size_t)N_NODES*4));
  int*   bsums = (int*)  (ws + take(256));
  int*   flag  = (int*)  (ws + take(256));
  (void)ws_size; (void)in_sizes; (void)n_in; (void)out_size;

  const int NB_N   = (N_NODES + 255)/256;
  const int NB_E   = (NEDGE   + 255)/256;
  const int NB_SC  = (N_NODES + 1023)/1024;
  const int NB_T64 = (N_NODES + 63)/64;     // 782
  const int NB_PK  = (442368 + 98304 + 8192)/256;

  k_detect<<<1, 64, 0, stream>>>(ei, flag);
  k_zero  <<<NB_N, 256, 0, stream>>>(deg, N_NODES);
  k_deg   <<<NB_E, 256, 0, stream>>>(ei, flag, deg);
  k_scan1 <<<NB_SC, 256, 0, stream>>>(deg, rp, bsums);
  k_scan2 <<<1, 64, 0, stream>>>(bsums, NB_SC);
  k_scan3 <<<NB_N+1, 256, 0, stream>>>(rp, cur, idg, deg, bsums);
  k_fill  <<<NB_E, 256, 0, stream>>>(ei, flag, cur, col);
  k_pack  <<<NB_PK, 256, 0, stream>>>(tw, wl, wr, cw, wp, wg, cwt);

  for (int l=0; l<NLAYER; l++){
    k_convm<<<NB_T64, 256, 0, stream>>>(x, xhi, xlo, (l>0) ? 1 : 0,
                                        wp + (size_t)l*294912, tb + l*128, hhi, hlo);
    k_agg  <<<N_NODES/4, 256, 0, stream>>>(hhi, rp, col, idg, ahi, alo);
    k_gemmm<<<NB_T64, 256, 0, stream>>>(ahi, alo, hhi, hlo, wg + (size_t)l*65536,
                                        bl + l*128, bng + l*128, bnb + l*128,
                                        bnm + l*128, bnv + l*128, xhi, xlo);
  }
  k_clf<<<NB_T64, 256, 0, stream>>>(xhi, xlo, cwt, cb, out);
}

// Round 14
// 475.528 us; speedup vs baseline: 1.0558x; 1.0558x over previous
//
#include <hip/hip_runtime.h>
#include <cstddef>
#include <cstdint>

// STGCN v6: v4 + hardware-async LDS staging (v5's reg-staging spilled: WRITE_SIZE
// 25->66MB scratch traffic; reverted). global_load_lds(16B) into LINEAR dual-buffer
// LDS; XOR swizzle moved to the GLOBAL source address (same involution as the
// read side - rule #21). Next half/phase staged right after the barrier; vmcnt
// drains at the following barrier (one full compute phase of cover, 0 VGPRs).
// Edge blocks + conv layer 0 (fp32 cvt8) use v4 manual staging into same layout.
// B prefetch back to v4's 1-deep. agg/clf/CSR unchanged from v4 (474.8us).

#define N_NODES 50000
#define FDIM    128
#define OUTC    64
#define NLAYER  3
#define KW      9
#define PADW    4
#define NEDGE   600000
#define BN_EPS  1e-5f

typedef short bf16x8 __attribute__((ext_vector_type(8)));
typedef float f32x4  __attribute__((ext_vector_type(4)));

__device__ __forceinline__ float relu_(float v){ return v > 0.f ? v : 0.f; }

__device__ __forceinline__ unsigned short bf_rne(float x){
  unsigned u = __float_as_uint(x);
  unsigned r = u + 0x7fff + ((u >> 16) & 1);
  return (unsigned short)(r >> 16);
}
__device__ __forceinline__ unsigned short bf_hi(float x, float& rem){
  unsigned short h = bf_rne(x);
  rem = x - __uint_as_float(((unsigned)h) << 16);
  return h;
}
__device__ __forceinline__ float bf2f(unsigned short u){
  return __uint_as_float(((unsigned)u) << 16);
}
__device__ __forceinline__ void cvt8(const float4& f0, const float4& f1, int4& hv, int4& lv){
  float f[8] = {f0.x,f0.y,f0.z,f0.w,f1.x,f1.y,f1.z,f1.w};
  unsigned short h[8], l[8];
  #pragma unroll
  for (int i=0;i<8;i++){ float r; h[i] = bf_hi(f[i], r); l[i] = bf_rne(r); }
  hv.x = (int)((unsigned)h[0] | ((unsigned)h[1]<<16));
  hv.y = (int)((unsigned)h[2] | ((unsigned)h[3]<<16));
  hv.z = (int)((unsigned)h[4] | ((unsigned)h[5]<<16));
  hv.w = (int)((unsigned)h[6] | ((unsigned)h[7]<<16));
  lv.x = (int)((unsigned)l[0] | ((unsigned)l[1]<<16));
  lv.y = (int)((unsigned)l[2] | ((unsigned)l[3]<<16));
  lv.z = (int)((unsigned)l[4] | ((unsigned)l[5]<<16));
  lv.w = (int)((unsigned)l[6] | ((unsigned)l[7]<<16));
}

// async 16B global -> LDS (LDS base wave-uniform; HW adds lane*16)
__device__ __forceinline__ void gl16(const unsigned short* g, unsigned short* l){
  __builtin_amdgcn_global_load_lds(
      (const __attribute__((address_space(1))) void*)g,
      (__attribute__((address_space(3))) void*)l, 16, 0, 0);
}

// ---------------- edge dtype detect + CSR build ----------------

__global__ void k_detect(const int* __restrict__ ei, int* __restrict__ flag){
  int t = threadIdx.x;
  unsigned long long b = __ballot(ei[2*t+1] == 0);
  if (t == 0) flag[0] = (b == ~0ull) ? 1 : 0;
}

__global__ void k_zero(int* __restrict__ p, int n){
  int i = blockIdx.x*256 + threadIdx.x;
  if (i < n) p[i] = 0;
}

__global__ void k_deg(const int* __restrict__ ei, const int* __restrict__ flag, int* __restrict__ deg){
  int e = blockIdx.x*256 + threadIdx.x;
  if (e >= NEDGE) return;
  int d = flag[0] ? ei[2*(NEDGE+e)] : ei[NEDGE+e];
  atomicAdd(&deg[d], 1);
}

__global__ void k_scan1(const int* __restrict__ deg, int* __restrict__ rp, int* __restrict__ bsums){
  __shared__ int sd[256];
  int t = threadIdx.x, base = blockIdx.x*1024 + t*4;
  int v0=0,v1=0,v2=0,v3=0;
  if (base+3 < N_NODES){ int4 q = *(const int4*)(deg+base); v0=q.x; v1=q.y; v2=q.z; v3=q.w; }
  else {
    if (base   < N_NODES) v0 = deg[base];
    if (base+1 < N_NODES) v1 = deg[base+1];
    if (base+2 < N_NODES) v2 = deg[base+2];
    if (base+3 < N_NODES) v3 = deg[base+3];
  }
  int s = v0+v1+v2+v3;
  sd[t] = s; __syncthreads();
  #pragma unroll
  for (int o=1;o<256;o<<=1){
    int x = (t>=o) ? sd[t-o] : 0;
    __syncthreads();
    sd[t] += x;
    __syncthreads();
  }
  int excl = sd[t]-s;
  if (base   < N_NODES) rp[base  ] = excl;
  if (base+1 < N_NODES) rp[base+1] = excl+v0;
  if (base+2 < N_NODES) rp[base+2] = excl+v0+v1;
  if (base+3 < N_NODES) rp[base+3] = excl+v0+v1+v2;
  if (t==255) bsums[blockIdx.x] = sd[255];
}

__global__ void k_scan2(int* __restrict__ bsums, int nb){
  if (threadIdx.x==0 && blockIdx.x==0){
    int run = 0;
    for (int i=0;i<nb;i++){ int x = bsums[i]; bsums[i] = run; run += x; }
  }
}

__global__ void k_scan3(int* __restrict__ rp, int* __restrict__ cur, float* __restrict__ idg,
                        const int* __restrict__ deg, const int* __restrict__ bsums){
  int i = blockIdx.x*256 + threadIdx.x;
  if (i < N_NODES){
    int r = rp[i] + bsums[i>>10];
    rp[i] = r; cur[i] = r;
    int d = deg[i];
    idg[i] = (d>0) ? 1.0f/(float)d : 0.0f;
  } else if (i == N_NODES){
    rp[N_NODES] = NEDGE;
  }
}

__global__ void k_fill(const int* __restrict__ ei, const int* __restrict__ flag,
                       int* __restrict__ cur, int* __restrict__ col){
  int e = blockIdx.x*256 + threadIdx.x;
  if (e >= NEDGE) return;
  int s,d;
  if (flag[0]){ s = ei[2*e]; d = ei[2*(NEDGE+e)]; }
  else        { s = ei[e];   d = ei[NEDGE+e];   }
  int pos = atomicAdd(&cur[d], 1);
  col[pos] = s;
}

// ---------------- weight prepack into MFMA fragment chunks ----------------

__global__ void k_pack(const float* __restrict__ tw, const float* __restrict__ wl,
                       const float* __restrict__ wr, const float* __restrict__ cw,
                       unsigned short* __restrict__ wp, unsigned short* __restrict__ wg,
                       float* __restrict__ cwt){
  int i = blockIdx.x*256 + threadIdx.x;
  const int T1v = 442368, T2v = 98304, T3v = 8192;
  if (i < T1v){
    int e = i & 7, lane = (i>>3)&63, ob = (i>>9)&7, cb = (i>>12)&3, kl = i>>14;
    int k = kl % KW, l = kl / KW;
    int o = ob*16 + (lane&15), c = cb*32 + (lane>>4)*8 + e;
    float v = tw[(((l*128+o)*128+c)*KW) + k];
    float rem; unsigned short hi = bf_hi(v, rem); unsigned short lo = bf_rne(rem);
    int chunk = (((l*KW+k)*4+cb)*8+ob)*2;
    wp[(size_t)chunk*512 + lane*8 + e]     = hi;
    wp[(size_t)(chunk+1)*512 + lane*8 + e] = lo;
  } else if (i < T1v+T2v){
    int i2 = i - T1v;
    int e = i2 & 7, lane = (i2>>3)&63, ob = (i2>>9)&7, ks = (i2>>12)&7, l = i2>>15;
    int o = ob*16 + (lane&15), j = ks*32 + (lane>>4)*8 + e;
    float v = (j < 128) ? wl[(l*128+o)*128 + j] : wr[(l*128+o)*128 + (j-128)];
    float rem; unsigned short hi = bf_hi(v, rem); unsigned short lo = bf_rne(rem);
    int chunk = ((l*8+ks)*8+ob)*2;
    wg[(size_t)chunk*512 + lane*8 + e]     = hi;
    wg[(size_t)(chunk+1)*512 + lane*8 + e] = lo;
  } else if (i < T1v+T2v+T3v){
    int j3 = i - (T1v+T2v);
    int o = j3 & 63, c = j3 >> 6;
    cwt[j3] = cw[o*128 + c];
  }
}

// ---------------- conv via MFMA: 64-node tile, dual-buffer async staging ------

#define CROWS 72
#define CPL   (CROWS*64)      // 4608 ushorts per plane

__global__ __launch_bounds__(256, 4) void k_convm(const float* __restrict__ xf,
                                                  const unsigned short* __restrict__ xhi,
                                                  const unsigned short* __restrict__ xlo,
                                                  const int use_planes,
                                                  const unsigned short* __restrict__ wpl,
                                                  const float* __restrict__ tb,
                                                  unsigned short* __restrict__ hhi,
                                                  unsigned short* __restrict__ hlo){
  __shared__ unsigned short sh[4*CPL];          // 2 buffers x (hi,lo) = 36864 B
  const int t = threadIdx.x;
  const int n0 = blockIdx.x*64;
  const int l = t & 63, w = t >> 6;
  const int l15 = l & 15, kg = l >> 4;
  const bf16x8* Bp = (const bf16x8*)wpl;
  // fast path: plane input and all rows n0-4 .. n0+67 in-bounds
  const int fast = use_planes && (n0 >= PADW) && (n0 + (CROWS-1-PADW) < N_NODES);

  f32x4 acc[4][2];
  #pragma unroll
  for (int rf=0;rf<4;rf++){ acc[rf][0] = (f32x4)0.f; acc[rf][1] = (f32x4)0.f; }

  auto stage = [&](int half, int buf){
    unsigned short* bb = sh + buf*2*CPL;
    if (fast){
      // linear LDS dest; source pre-swizzled with the read-side involution
      for (int qb = w*64; qb < CROWS*8; qb += 256){
        int q = qb + l;
        int row = q >> 3;
        int c8s = (q & 7) ^ (row & 7);
        size_t go = (size_t)(n0 - PADW + row)*FDIM + half*64 + c8s*8;
        gl16(xhi + go, bb + qb*8);
        gl16(xlo + go, bb + CPL + qb*8);
      }
    } else {
      for (int u = t; u < CROWS*8; u += 256){
        int row = u>>3, c8 = u&7;
        int gn = n0 - PADW + row;
        int4 hv = make_int4(0,0,0,0), lv = make_int4(0,0,0,0);
        if (gn >= 0 && gn < N_NODES){
          if (use_planes){
            size_t o = (size_t)gn*FDIM + half*64 + c8*8;
            hv = *(const int4*)(xhi + o);
            lv = *(const int4*)(xlo + o);
          } else {
            const float* src = xf + (size_t)gn*FDIM + half*64 + c8*8;
            float4 f0 = *(const float4*)src, f1 = *(const float4*)(src+4);
            cvt8(f0, f1, hv, lv);
          }
        }
        int idx = row*64 + ((c8 ^ (row&7)) << 3);
        *(int4*)&bb[idx] = hv;
        *(int4*)&bb[CPL + idx] = lv;
      }
    }
  };

  bf16x8 B00, B01, B10, B11;
  {
    int ch = ((0*4+0)*8 + 2*w)*2;
    B00 = Bp[ch*64 + l]; B01 = Bp[(ch+1)*64 + l];
    B10 = Bp[(ch+2)*64 + l]; B11 = Bp[(ch+3)*64 + l];
  }

  stage(0, 0);
  __syncthreads();              // buf0 ready (vmcnt+lgkm drained)
  stage(1, 1);                  // async: lands during half-0 compute

  for (int half = 0; half < 2; ++half){
    const unsigned short* bb = sh + half*2*CPL;
    for (int kk = 0; kk < 18; ++kk){
      int k = kk >> 1, cb2 = kk & 1;
      bf16x8 Bc00=B00, Bc01=B01, Bc10=B10, Bc11=B11;
      {
        int it = half*18 + kk;
        int itn = (it+1 < 36) ? it+1 : it;
        int halfn = itn/18, kkn = itn%18;
        int kn = kkn>>1, cb2n = kkn&1, cbgn = halfn*2 + cb2n;
        int ch = ((kn*4+cbgn)*8 + 2*w)*2;
        B00 = Bp[ch*64 + l]; B01 = Bp[(ch+1)*64 + l];
        B10 = Bp[(ch+2)*64 + l]; B11 = Bp[(ch+3)*64 + l];
      }
      int cc3 = cb2*4 + kg;
      int rowk = l15 + k;
      int base = rowk*64 + ((cc3 ^ (rowk&7)) << 3);
      #pragma unroll
      for (int rf = 0; rf < 4; ++rf){
        int idx = base + rf*16*64;
        bf16x8 Ah = *(const bf16x8*)&bb[idx];
        bf16x8 Al = *(const bf16x8*)&bb[CPL + idx];
        acc[rf][0] = __builtin_amdgcn_mfma_f32_16x16x32_bf16(Ah, Bc00, acc[rf][0], 0,0,0);
        acc[rf][0] = __builtin_amdgcn_mfma_f32_16x16x32_bf16(Ah, Bc01, acc[rf][0], 0,0,0);
        acc[rf][0] = __builtin_amdgcn_mfma_f32_16x16x32_bf16(Al, Bc00, acc[rf][0], 0,0,0);
        acc[rf][1] = __builtin_amdgcn_mfma_f32_16x16x32_bf16(Ah, Bc10, acc[rf][1], 0,0,0);
        acc[rf][1] = __builtin_amdgcn_mfma_f32_16x16x32_bf16(Ah, Bc11, acc[rf][1], 0,0,0);
        acc[rf][1] = __builtin_amdgcn_mfma_f32_16x16x32_bf16(Al, Bc10, acc[rf][1], 0,0,0);
      }
    }
    if (half == 0) __syncthreads();   // drains buf1's async loads
  }

  int o0 = w*32 + l15, o1 = o0 + 16;
  float tb0 = tb[o0], tb1 = tb[o1];
  #pragma unroll
  for (int rf = 0; rf < 4; ++rf){
    #pragma unroll
    for (int j = 0; j < 4; ++j){
      int n = n0 + rf*16 + kg*4 + j;
      if (n < N_NODES){
        float v0 = relu_(acc[rf][0][j] + tb0);
        float v1 = relu_(acc[rf][1][j] + tb1);
        float r0, r1;
        unsigned short h0 = bf_hi(v0, r0), h1 = bf_hi(v1, r1);
        size_t b = (size_t)n*FDIM;
        hhi[b+o0] = h0; hlo[b+o0] = bf_rne(r0);
        hhi[b+o1] = h1; hlo[b+o1] = bf_rne(r1);
      }
    }
  }
}

// ---------------- SAGE mean aggregation: bf16-hi gather (as v4) ----------------

__global__ __launch_bounds__(256) void k_agg(const unsigned short* __restrict__ hhi,
                                             const int* __restrict__ rp,
                                             const int* __restrict__ col,
                                             const float* __restrict__ idg,
                                             unsigned short* __restrict__ ahi,
                                             unsigned short* __restrict__ alo){
  int n = blockIdx.x*4 + (threadIdx.x>>6);
  int lane = threadIdx.x & 63;
  int half = lane >> 5, li = lane & 31;
  if (n >= N_NODES) return;
  int s0 = rp[n], s1 = rp[n+1];
  float a0=0.f, a1=0.f, a2=0.f, a3=0.f;
  int e = s0 + half;
  for (; e + 2 < s1; e += 4){
    int sA = col[e], sB = col[e+2];
    ushort4 vA = *(const ushort4*)(hhi + (size_t)sA*FDIM + li*4);
    ushort4 vB = *(const ushort4*)(hhi + (size_t)sB*FDIM + li*4);
    a0 += bf2f(vA.x) + bf2f(vB.x);
    a1 += bf2f(vA.y) + bf2f(vB.y);
    a2 += bf2f(vA.z) + bf2f(vB.z);
    a3 += bf2f(vA.w) + bf2f(vB.w);
  }
  for (; e < s1; e += 2){
    int s = col[e];
    ushort4 v = *(const ushort4*)(hhi + (size_t)s*FDIM + li*4);
    a0 += bf2f(v.x); a1 += bf2f(v.y); a2 += bf2f(v.z); a3 += bf2f(v.w);
  }
  a0 += __shfl_xor(a0, 32);
  a1 += __shfl_xor(a1, 32);
  a2 += __shfl_xor(a2, 32);
  a3 += __shfl_xor(a3, 32);
  float wv = idg[n];
  a0 *= wv; a1 *= wv; a2 *= wv; a3 *= wv;
  float r0,r1,r2,r3;
  unsigned short h0 = bf_hi(a0,r0), h1 = bf_hi(a1,r1), h2 = bf_hi(a2,r2), h3 = bf_hi(a3,r3);
  size_t b = (size_t)n*FDIM + li*4;
  if (half == 0){
    ushort4 o; o.x=h0; o.y=h1; o.z=h2; o.w=h3;
    *(ushort4*)(ahi + b) = o;
  } else {
    ushort4 o; o.x=bf_rne(r0); o.y=bf_rne(r1); o.z=bf_rne(r2); o.w=bf_rne(r3);
    *(ushort4*)(alo + b) = o;
  }
}

// ---------------- SAGE linear + BN + ReLU: dual-buffer async staging ----------

#define GPL (64*64)           // 4096 ushorts per plane

__global__ __launch_bounds__(256, 4) void k_gemmm(const unsigned short* __restrict__ ahi,
                                                  const unsigned short* __restrict__ alo,
                                                  const unsigned short* __restrict__ hhi,
                                                  const unsigned short* __restrict__ hlo,
                                                  const unsigned short* __restrict__ wgl,
                                                  const float* __restrict__ bl,
                                                  const float* __restrict__ bng, const float* __restrict__ bnb,
                                                  const float* __restrict__ bnm, const float* __restrict__ bnv,
                                                  unsigned short* __restrict__ xhi,
                                                  unsigned short* __restrict__ xlo){
  __shared__ unsigned short sh[4*GPL];          // 2 buffers x (hi,lo) = 32768 B
  const int t = threadIdx.x;
  const int n0 = blockIdx.x*64;
  const int l = t & 63, w = t >> 6;
  const int l15 = l & 15, kg = l >> 4;
  const bf16x8* Bp = (const bf16x8*)wgl;
  const int fast = (n0 + 63 < N_NODES);

  f32x4 acc[4][2];
  #pragma unroll
  for (int rf=0;rf<4;rf++){ acc[rf][0] = (f32x4)0.f; acc[rf][1] = (f32x4)0.f; }

  auto stage = [&](int p, int buf){
    unsigned short* bb = sh + buf*2*GPL;
    const unsigned short* shi = (p >= 2) ? hhi : ahi;
    const unsigned short* slo = (p >= 2) ? hlo : alo;
    int ch0 = (p & 1)*64;
    if (fast){
      for (int qb = w*64; qb < 64*8; qb += 256){
        int q = qb + l;
        int row = q >> 3;
        int c8s = (q & 7) ^ (row & 7);
        size_t go = (size_t)(n0 + row)*FDIM + ch0 + c8s*8;
        gl16(shi + go, bb + qb*8);
        gl16(slo + go, bb + GPL + qb*8);
      }
    } else {
      for (int u = t; u < 64*8; u += 256){
        int row = u>>3, c8 = u&7;
        int gn = n0 + row;
        int4 hv = make_int4(0,0,0,0), lv = make_int4(0,0,0,0);
        if (gn < N_NODES){
          size_t o = (size_t)gn*FDIM + ch0 + c8*8;
          hv = *(const int4*)(shi + o);
          lv = *(const int4*)(slo + o);
        }
        int idx = row*64 + ((c8 ^ (row&7)) << 3);
        *(int4*)&bb[idx] = hv;
        *(int4*)&bb[GPL + idx] = lv;
      }
    }
  };

  bf16x8 B00, B01, B10, B11;
  {
    int ch = (0*8 + 2*w)*2;
    B00 = Bp[ch*64 + l]; B01 = Bp[(ch+1)*64 + l];
    B10 = Bp[(ch+2)*64 + l]; B11 = Bp[(ch+3)*64 + l];
  }

  stage(0, 0);
  __syncthreads();

  for (int p = 0; p < 4; ++p){
    if (p < 3) stage(p+1, (p+1)&1);   // async; previous buffer's reads finished at last barrier
    const unsigned short* bb = sh + (p&1)*2*GPL;
    for (int cb2 = 0; cb2 < 2; ++cb2){
      bf16x8 Bc00=B00, Bc01=B01, Bc10=B10, Bc11=B11;
      {
        int ks = p*2 + cb2;
        int ksn = (ks+1 < 8) ? ks+1 : ks;
        int ch = (ksn*8 + 2*w)*2;
        B00 = Bp[ch*64 + l]; B01 = Bp[(ch+1)*64 + l];
        B10 = Bp[(ch+2)*64 + l]; B11 = Bp[(ch+3)*64 + l];
      }
      int cc3 = cb2*4 + kg;
      int base = l15*64 + ((cc3 ^ (l15&7)) << 3);
      #pragma unroll
      for (int rf = 0; rf < 4; ++rf){
        int idx = base + rf*16*64;
        bf16x8 Ah = *(const bf16x8*)&bb[idx];
        bf16x8 Al = *(const bf16x8*)&bb[GPL + idx];
        acc[rf][0] = __builtin_amdgcn_mfma_f32_16x16x32_bf16(Ah, Bc00, acc[rf][0], 0,0,0);
        acc[rf][0] = __builtin_amdgcn_mfma_f32_16x16x32_bf16(Ah, Bc01, acc[rf][0], 0,0,0);
        acc[rf][0] = __builtin_amdgcn_mfma_f32_16x16x32_bf16(Al, Bc00, acc[rf][0], 0,0,0);
        acc[rf][1] = __builtin_amdgcn_mfma_f32_16x16x32_bf16(Ah, Bc10, acc[rf][1], 0,0,0);
        acc[rf][1] = __builtin_amdgcn_mfma_f32_16x16x32_bf16(Ah, Bc11, acc[rf][1], 0,0,0);
        acc[rf][1] = __builtin_amdgcn_mfma_f32_16x16x32_bf16(Al, Bc10, acc[rf][1], 0,0,0);
      }
    }
    if (p < 3) __syncthreads();       // drains next buffer's async loads
  }

  int o0 = w*32 + l15, o1 = o0 + 16;
  float s0 = bng[o0]*rsqrtf(bnv[o0]+BN_EPS);
  float c0 = bnb[o0] + s0*(bl[o0]-bnm[o0]);
  float s1 = bng[o1]*rsqrtf(bnv[o1]+BN_EPS);
  float c1 = bnb[o1] + s1*(bl[o1]-bnm[o1]);
  #pragma unroll
  for (int rf = 0; rf < 4; ++rf){
    #pragma unroll
    for (int j = 0; j < 4; ++j){
      int n = n0 + rf*16 + kg*4 + j;
      if (n < N_NODES){
        float v0 = relu_(s0*acc[rf][0][j] + c0);
        float v1 = relu_(s1*acc[rf][1][j] + c1);
        float r0, r1;
        unsigned short h0 = bf_hi(v0, r0), h1 = bf_hi(v1, r1);
        size_t b = (size_t)n*FDIM;
        xhi[b+o0] = h0; xlo[b+o0] = bf_rne(r0);
        xhi[b+o1] = h1; xlo[b+o1] = bf_rne(r1);
      }
    }
  }
}

// ---------------- classifier + log_softmax (as v4) ----------------

__global__ __launch_bounds__(256) void k_clf(const unsigned short* __restrict__ xhi,
                                             const unsigned short* __restrict__ xlo,
                                             const float* __restrict__ cwt,
                                             const float* __restrict__ cb, float* __restrict__ out){
  __shared__ float As[128][68];
  __shared__ float mxl[64];
  const int t = threadIdx.x, n0 = blockIdx.x*64;
  const int ng = t & 15, og = t>>4;
  float acc[4][4];
  #pragma unroll
  for (int i=0;i<4;i++)
    #pragma unroll
    for (int j=0;j<4;j++) acc[i][j] = 0.f;

  for (int u=t; u<64*16; u+=256){
    int row = u>>4, c16 = u&15;
    int gn = n0 + row;
    int4 hv = make_int4(0,0,0,0), lv = make_int4(0,0,0,0);
    if (gn < N_NODES){
      size_t o = (size_t)gn*FDIM + c16*8;
      hv = *(const int4*)(xhi + o);
      lv = *(const int4*)(xlo + o);
    }
    const unsigned short* hs = (const unsigned short*)&hv;
    const unsigned short* ls = (const unsigned short*)&lv;
    #pragma unroll
    for (int j=0;j<8;j++) As[c16*8+j][row] = bf2f(hs[j]) + bf2f(ls[j]);
  }
  __syncthreads();
  #pragma unroll 2
  for (int c=0;c<128;c++){
    float aa[4] = {As[c][ng], As[c][ng+16], As[c][ng+32], As[c][ng+48]};
    float4 b = *(const float4*)(cwt + c*64 + og*4);
    float bb[4] = {b.x,b.y,b.z,b.w};
    #pragma unroll
    for (int i=0;i<4;i++)
      #pragma unroll
      for (int j=0;j<4;j++) acc[i][j] = fmaf(aa[i], bb[j], acc[i][j]);
  }
  __syncthreads();
  float4 cb4 = *(const float4*)(cb + og*4);
  float cbv[4] = {cb4.x,cb4.y,cb4.z,cb4.w};
  #pragma unroll
  for (int i=0;i<4;i++)
    #pragma unroll
    for (int j=0;j<4;j++) As[ng+16*i][og*4+j] = acc[i][j] + cbv[j];
  __syncthreads();
  if (t < 64){
    float mx = -1e30f;
    #pragma unroll 8
    for (int o=0;o<64;o++) mx = fmaxf(mx, As[t][o]);
    float se = 0.f;
    #pragma unroll 8
    for (int o=0;o<64;o++) se += expf(As[t][o]-mx);
    mxl[t] = mx + logf(se);
  }
  __syncthreads();
  #pragma unroll
  for (int v=0;v<4;v++){
    int q = t + v*256;
    int r = q>>4, o4 = (q&15)*4;
    int n = n0 + r;
    if (n < N_NODES){
      float4 L = *(const float4*)&As[r][o4];
      float m = mxl[r];
      float4 wv; wv.x = L.x-m; wv.y = L.y-m; wv.z = L.z-m; wv.w = L.w-m;
      *(float4*)(out + (size_t)n*OUTC + o4) = wv;
    }
  }
}

// ---------------- launch ----------------

extern "C" void kernel_launch(void* const* d_in, const int* in_sizes, int n_in,
                              void* d_out, int out_size, void* d_ws, size_t ws_size,
                              hipStream_t stream) {
  const float* x   = (const float*)d_in[0];
  const int*   ei  = (const int*)  d_in[1];
  const float* tw  = (const float*)d_in[2];
  const float* tb  = (const float*)d_in[3];
  const float* wl  = (const float*)d_in[4];
  const float* bl  = (const float*)d_in[5];
  const float* wr  = (const float*)d_in[6];
  const float* bng = (const float*)d_in[7];
  const float* bnb = (const float*)d_in[8];
  const float* bnm = (const float*)d_in[9];
  const float* bnv = (const float*)d_in[10];
  const float* cw  = (const float*)d_in[11];
  const float* cb  = (const float*)d_in[12];
  float* out = (float*)d_out;
  char* ws = (char*)d_ws;

  auto align256 = [](size_t v){ return (v + 255) & ~(size_t)255; };
  size_t off = 0;
  auto take = [&](size_t bytes){ size_t o = off; off += align256(bytes); return o; };
  const size_t PLANE = (size_t)N_NODES*FDIM*2;              // 12.8 MB
  unsigned short* xhi = (unsigned short*)(ws + take(PLANE));
  unsigned short* xlo = (unsigned short*)(ws + take(PLANE));
  unsigned short* hhi = (unsigned short*)(ws + take(PLANE));
  unsigned short* hlo = (unsigned short*)(ws + take(PLANE));
  unsigned short* ahi = (unsigned short*)(ws + take(PLANE));
  unsigned short* alo = (unsigned short*)(ws + take(PLANE));
  unsigned short* wp  = (unsigned short*)(ws + take((size_t)884736*2));
  unsigned short* wg  = (unsigned short*)(ws + take((size_t)196608*2));
  float* cwt   = (float*)(ws + take((size_t)128*64*4));
  int*   deg   = (int*)  (ws + take((size_t)N_NODES*4));
  int*   rp    = (int*)  (ws + take((size_t)(N_NODES+1)*4));
  int*   cur   = (int*)  (ws + take((size_t)N_NODES*4));
  int*   col   = (int*)  (ws + take((size_t)NEDGE*4));
  float* idg   = (float*)(ws + take((size_t)N_NODES*4));
  int*   bsums = (int*)  (ws + take(256));
  int*   flag  = (int*)  (ws + take(256));
  (void)ws_size; (void)in_sizes; (void)n_in; (void)out_size;

  const int NB_N   = (N_NODES + 255)/256;
  const int NB_E   = (NEDGE   + 255)/256;
  const int NB_SC  = (N_NODES + 1023)/1024;
  const int NB_T64 = (N_NODES + 63)/64;     // 782
  const int NB_PK  = (442368 + 98304 + 8192)/256;

  k_detect<<<1, 64, 0, stream>>>(ei, flag);
  k_zero  <<<NB_N, 256, 0, stream>>>(deg, N_NODES);
  k_deg   <<<NB_E, 256, 0, stream>>>(ei, flag, deg);
  k_scan1 <<<NB_SC, 256, 0, stream>>>(deg, rp, bsums);
  k_scan2 <<<1, 64, 0, stream>>>(bsums, NB_SC);
  k_scan3 <<<NB_N+1, 256, 0, stream>>>(rp, cur, idg, deg, bsums);
  k_fill  <<<NB_E, 256, 0, stream>>>(ei, flag, cur, col);
  k_pack  <<<NB_PK, 256, 0, stream>>>(tw, wl, wr, cw, wp, wg, cwt);

  for (int l=0; l<NLAYER; l++){
    k_convm<<<NB_T64, 256, 0, stream>>>(x, xhi, xlo, (l>0) ? 1 : 0,
                                        wp + (size_t)l*294912, tb + l*128, hhi, hlo);
    k_agg  <<<N_NODES/4, 256, 0, stream>>>(hhi, rp, col, idg, ahi, alo);
    k_gemmm<<<NB_T64, 256, 0, stream>>>(ahi, alo, hhi, hlo, wg + (size_t)l*65536,
                                        bl + l*128, bng + l*128, bnb + l*128,
                                        bnm + l*128, bnv + l*128, xhi, xlo);
  }
  k_clf<<<NB_T64, 256, 0, stream>>>(xhi, xlo, cwt, cb, out);
}